// Round 10
// baseline (1503.993 us; speedup 1.0000x reference)
//
#include <hip/hip_runtime.h>
#include <hip/hip_bf16.h>
#include <math.h>

#define BB 8
#define SS 1024
#define DD 768
#define HH 12
#define LL 6
#define FF 3072
#define CC 10
#define BS_ (BB * SS)   // 8192 rows

typedef __attribute__((ext_vector_type(8))) short short8v;       // bf16x8 MFMA frag
typedef __attribute__((ext_vector_type(4))) float f32x4;         // 16x16 MFMA acc
typedef __attribute__((ext_vector_type(16))) float f32x16;       // 32x32 MFMA acc
typedef __attribute__((ext_vector_type(8))) unsigned short ushort8v;
typedef __attribute__((ext_vector_type(4))) unsigned short ushort4v;
typedef __attribute__((ext_vector_type(4))) unsigned int uint4v;

#define CEXPQ 0.18033688f   // 0.125 * log2(e), folded into Q at the QKV epilogue

__device__ inline unsigned short f2bf(float f) {
  unsigned int u = __builtin_bit_cast(unsigned int, f);
  u += 0x7fffu + ((u >> 16) & 1u);
  return (unsigned short)(u >> 16);
}
__device__ inline float bf2f(unsigned short u) {
  return __builtin_bit_cast(float, (unsigned int)u << 16);
}
__device__ inline unsigned int cvtpk(float lo, float hi) {
  unsigned int r;
  asm("v_cvt_pk_bf16_f32 %0, %1, %2" : "=v"(r) : "v"(lo), "v"(hi));
  return r;
}
__device__ inline void plswap(unsigned int& a, unsigned int& b) {
  asm volatile("v_permlane32_swap_b32 %0, %1" : "+v"(a), "+v"(b));
}
__device__ inline void gload16(const void* g, void* l) {
  __builtin_amdgcn_global_load_lds((const __attribute__((address_space(1))) void*)g,
                                   (__attribute__((address_space(3))) void*)l, 16, 0, 0);
}

// ---------------- reduction helpers ----------------
__device__ inline float wave_sum(float v) {
#pragma unroll
  for (int off = 32; off > 0; off >>= 1) v += __shfl_down(v, off);
  return v;
}

// ---------------- embedding + sinusoidal PE (bf16 stream) ----------------
__global__ __launch_bounds__(256) void k_embed(const int* __restrict__ tokens,
                                               const float* __restrict__ emb,
                                               ushort* __restrict__ xb) {
  int row = blockIdx.x;
  int s = row & (SS - 1);
  int tok = tokens[row];
  const float* e = emb + (size_t)tok * DD;
  ushort* xbr = xb + (size_t)row * DD;
  for (int d = threadIdx.x; d < DD; d += 256) {
    float freq = expf((float)(d & ~1) * -0.0119926306f);
    float ang = (float)s * freq;
    float pe = (d & 1) ? cosf(ang) : sinf(ang);
    xbr[d] = f2bf(e[d] + pe);
  }
}

// ---------------- fused per-layer weight transpose ----------------
__global__ __launch_bounds__(256) void k_transpose_all(
    const float* __restrict__ wq, const float* __restrict__ wk,
    const float* __restrict__ wv, const float* __restrict__ wo,
    const float* __restrict__ w1, const float* __restrict__ w2,
    ushort* __restrict__ wqkv_t, ushort* __restrict__ wo_t,
    ushort* __restrict__ w1_t, ushort* __restrict__ w2_t) {
  __shared__ float tile[32][33];
  int bid = blockIdx.x;
  const float* W; ushort* Wt; int K, N, lb;
  if (bid < 1728) {
    int m = bid / 576; lb = bid - m * 576;
    W = (m == 0) ? wq : (m == 1) ? wk : wv;
    Wt = wqkv_t + m * 768 * 768; K = 768; N = 768;
  } else if (bid < 2304) {
    W = wo; Wt = wo_t; K = 768; N = 768; lb = bid - 1728;
  } else if (bid < 4608) {
    W = w1; Wt = w1_t; K = 768; N = 3072; lb = bid - 2304;
  } else {
    W = w2; Wt = w2_t; K = 3072; N = 768; lb = bid - 4608;
  }
  int nbk = K >> 5;
  int k0 = (lb % nbk) * 32, n0 = (lb / nbk) * 32;
  int t = threadIdx.x;
  int r = t >> 3, c4 = (t & 7) * 4;
  float4 v = *(const float4*)(W + (size_t)(k0 + r) * N + n0 + c4);
  tile[r][c4 + 0] = v.x; tile[r][c4 + 1] = v.y;
  tile[r][c4 + 2] = v.z; tile[r][c4 + 3] = v.w;
  __syncthreads();
  ushort4v o;
#pragma unroll
  for (int i = 0; i < 4; ++i) o[i] = f2bf(tile[c4 + i][r]);
  *(ushort4v*)(Wt + (size_t)(n0 + r) * K + k0 + c4) = o;
}

// ---------------- bf16 MFMA GEMM, double-buffered + T2 XOR-swizzled LDS ----------------
// SCALEQ: multiply output cols < 768 by CEXPQ (folds softmax scale into Q).
template <int RELU, int TN, int SCALEQ = 0>
__global__ __launch_bounds__(256) void k_gemm_db(const ushort* __restrict__ A,
                                                 const ushort* __restrict__ Bt,
                                                 ushort* __restrict__ Cout,
                                                 int M, int N, int K) {
  constexpr int NF = TN / 32;            // B frags per wave
  __shared__ ushort smem[2][(128 + TN) * 64];
  int bidl = blockIdx.y * gridDim.x + blockIdx.x;
  int nwg = gridDim.x * gridDim.y;
  int cpx = nwg >> 3;
  int tid = (bidl & 7) * cpx + (bidl >> 3);
  int n0 = (tid % gridDim.x) * TN, m0 = (tid / gridDim.x) * 128;
  int t = threadIdx.x, w = t >> 6, l = t & 63;
  int wr = (w >> 1) * 64, wc = (w & 1) * (TN / 2);
  int lr = l & 15, lg = l >> 4;
  f32x4 acc[4][NF] = {};
  int sr8 = l >> 3;
  int scw = ((l & 7) ^ sr8) * 8;          // inverse-swizzled source col
  const ushort* ag = A + (size_t)(m0 + w * 8 + sr8) * K + scw;
  const ushort* bg = Bt + (size_t)(n0 + w * 8 + sr8) * K + scw;
  int nk = K >> 6;
  {
    ushort* al = &smem[0][(w * 8) * 64];
    ushort* bl = &smem[0][128 * 64 + (w * 8) * 64];
#pragma unroll
    for (int ii = 0; ii < 4; ++ii) gload16(ag + (size_t)ii * 32 * K, al + ii * 2048);
#pragma unroll
    for (int ii = 0; ii < TN / 32; ++ii) gload16(bg + (size_t)ii * 32 * K, bl + ii * 2048);
  }
  int rsw = lr & 7;
  for (int k = 0; k < nk; ++k) {
    __syncthreads();
    if (k + 1 < nk) {
      int kb = (k + 1) & 1;
      int kc0 = (k + 1) * 64;
      ushort* al = &smem[kb][(w * 8) * 64];
      ushort* bl = &smem[kb][128 * 64 + (w * 8) * 64];
#pragma unroll
      for (int ii = 0; ii < 4; ++ii) gload16(ag + (size_t)ii * 32 * K + kc0, al + ii * 2048);
#pragma unroll
      for (int ii = 0; ii < TN / 32; ++ii) gload16(bg + (size_t)ii * 32 * K + kc0, bl + ii * 2048);
    }
    const ushort* As = &smem[k & 1][0];
    const ushort* Bs = &smem[k & 1][128 * 64];
#pragma unroll
    for (int ks = 0; ks < 2; ++ks) {
      short8v af[4], bfr[NF];
#pragma unroll
      for (int mi = 0; mi < 4; ++mi)
        af[mi] = *(const short8v*)(As + (wr + mi * 16 + lr) * 64 + (((ks * 4 + lg) ^ rsw) << 3));
#pragma unroll
      for (int ni = 0; ni < NF; ++ni)
        bfr[ni] = *(const short8v*)(Bs + (wc + ni * 16 + lr) * 64 + (((ks * 4 + lg) ^ rsw) << 3));
      __builtin_amdgcn_s_setprio(1);
#pragma unroll
      for (int mi = 0; mi < 4; ++mi)
#pragma unroll
        for (int ni = 0; ni < NF; ++ni)
          acc[mi][ni] = __builtin_amdgcn_mfma_f32_16x16x32_bf16(af[mi], bfr[ni], acc[mi][ni], 0, 0, 0);
      __builtin_amdgcn_s_setprio(0);
    }
  }
  __syncthreads();
  float osc = (SCALEQ && n0 < 768) ? CEXPQ : 1.0f;
  ushort* cst = &smem[0][0];
#pragma unroll
  for (int mi = 0; mi < 4; ++mi)
#pragma unroll
    for (int ni = 0; ni < NF; ++ni) {
      int cl = wc + ni * 16 + lr;
#pragma unroll
      for (int i = 0; i < 4; ++i) {
        int rl = wr + mi * 16 + lg * 4 + i;
        float v = acc[mi][ni][i];
        if (RELU) v = fmaxf(v, 0.f);
        if (SCALEQ) v *= osc;
        cst[rl * TN + (cl ^ (((rl >> 2) & 3) << 4))] = f2bf(v);
      }
    }
  __syncthreads();
  {
    int row = t >> 1, half = t & 1;
    int swr = ((row >> 2) & 3) << 4;
    ushort* crow = Cout + (size_t)(m0 + row) * N + n0 + half * (TN / 2);
#pragma unroll
    for (int c8 = 0; c8 < TN / 16; ++c8) {
      int c = half * (TN / 2) + c8 * 8;
      ushort8v vv = *(const ushort8v*)(&cst[row * TN + (c ^ swr)]);
      *(ushort8v*)(crow + c8 * 8) = vv;
    }
  }
}

// ---------------- flash attention: 8 waves, Q-tile 256, 32x32 MFMA, in-reg P ----------------
// Per-wave math identical to the verified r9 kernel; staging split across 8
// waves (1 gload16/wave/tile for K; half V work). Q pre-scaled by CEXPQ.
__global__ __launch_bounds__(512) void k_flash(const ushort* __restrict__ qkv,
                                               ushort* __restrict__ ao) {
  __shared__ ushort lds[16384];       // Ks[2][64][64] | Vt[2][64][64]
  ushort* KsB = lds;
  ushort* VtB = lds + 8192;
  const int LD = 2304;
  int bidl = blockIdx.y * gridDim.x + blockIdx.x;   // 4 x 96 = 384
  int tid = (bidl & 7) * 48 + (bidl >> 3);
  int qt = tid & 3;
  int bh = tid >> 2;                  // 12 bh per XCD -> 3MB KV in its L2
  int hd = bh % HH, b = bh / HH;
  int t = threadIdx.x, w = t >> 6, l = t & 63;
  int q = l & 31, hl = l >> 5;
  int q0 = qt * 256;
  const ushort* qbase = qkv + (size_t)(b * SS) * LD + hd * 64;
  const ushort* kbase = qbase + 768;
  const ushort* vbase = qbase + 1536;
  short8v qfb[4];
  {
    const ushort* qrow = qbase + (size_t)(q0 + w * 32 + q) * LD + hl * 8;
    qfb[0] = *(const short8v*)(qrow);
    qfb[1] = *(const short8v*)(qrow + 16);
    qfb[2] = *(const short8v*)(qrow + 32);
    qfb[3] = *(const short8v*)(qrow + 48);
  }
  float l_run = 0.f;
  f32x16 o_acc[2] = {};
  // K staging: wave w rows [w*8, w*8+8), 1 gload16; source granule pre-swizzled
  // by swz(row) = (row&7) ^ ((row>>3)&3), row>>3 == w here.
  int r8_ = l >> 3;
  const ushort* kg = kbase + (size_t)(w * 8 + r8_) * LD +
                     (((l & 7) ^ r8_ ^ (w & 3)) * 8);
  // V staging: thread covers dk rows d4..d4+3, kv pair kv2
  int d4 = (t & 15) * 4;
  int kv2 = (t >> 4) * 2;
  const ushort* vg = vbase + (size_t)kv2 * LD + d4;
  {  // prologue: stage tile 0 into buf 0
    gload16(kg, KsB + (w * 8) * 64);
    ushort4v v0 = *(const ushort4v*)(vg);
    ushort4v v1 = *(const ushort4v*)(vg + LD);
#pragma unroll
    for (int i = 0; i < 4; ++i) {
      int row = d4 + i;
      int swz = ((row & 7) ^ ((row >> 3) & 7)) & 7;
      *(unsigned int*)(VtB + row * 64 + (kv2 ^ (swz << 3))) =
          (unsigned int)v0[i] | ((unsigned int)v1[i] << 16);
    }
  }
  for (int kt = 0; kt < 16; ++kt) {
    int cur = kt & 1, nxt = cur ^ 1;
    __syncthreads();     // buf[cur] staged (implicit vmcnt/lgkm drain)
    ushort4v v0n, v1n;
    if (kt < 15) {       // issue next-tile loads
      size_t off = (size_t)(kt + 1) * 64 * LD;
      gload16(kg + off, KsB + nxt * 4096 + (w * 8) * 64);
      v0n = *(const ushort4v*)(vg + off);
      v1n = *(const ushort4v*)(vg + off + LD);
    }
    // S^T[kv 64][q 32] = K · Q^T
    f32x16 s[2] = {};
    __builtin_amdgcn_s_setprio(1);
#pragma unroll
    for (int c = 0; c < 4; ++c)
#pragma unroll
      for (int mi = 0; mi < 2; ++mi) {
        int gr = ((c << 1) | hl) ^ (l & 7) ^ ((l >> 3) & 3);
        short8v kf = *(const short8v*)(KsB + cur * 4096 + (mi * 32 + q) * 64 + (gr << 3));
        s[mi] = __builtin_amdgcn_mfma_f32_32x32x16_bf16(kf, qfb[c], s[mi], 0, 0, 0);
      }
    __builtin_amdgcn_s_setprio(0);
    // softmax (no-max, scale pre-folded into Q): p = exp2(s)
    float psum = 0.f;
#pragma unroll
    for (int mi = 0; mi < 2; ++mi)
#pragma unroll
      for (int r = 0; r < 16; ++r) {
        float e = exp2f(s[mi][r]);
        s[mi][r] = e;
        psum += e;
      }
    psum += __shfl_xor(psum, 32);
    l_run += psum;
    // rebuild P^T B-frags in registers (cvt_pk + permlane32_swap)
    short8v pfb[4];
#pragma unroll
    for (int mi = 0; mi < 2; ++mi)
#pragma unroll
      for (int k2 = 0; k2 < 2; ++k2) {
        unsigned int a0 = cvtpk(s[mi][8 * k2 + 0], s[mi][8 * k2 + 1]);
        unsigned int a1 = cvtpk(s[mi][8 * k2 + 2], s[mi][8 * k2 + 3]);
        unsigned int b0 = cvtpk(s[mi][8 * k2 + 4], s[mi][8 * k2 + 5]);
        unsigned int b1 = cvtpk(s[mi][8 * k2 + 6], s[mi][8 * k2 + 7]);
        plswap(a0, b0);
        plswap(a1, b1);
        uint4v u;
        u[0] = a0; u[1] = a1; u[2] = b0; u[3] = b1;
        pfb[mi * 2 + k2] = __builtin_bit_cast(short8v, u);
      }
    // write next V tile while PV runs on cur
    if (kt < 15) {
#pragma unroll
      for (int i = 0; i < 4; ++i) {
        int row = d4 + i;
        int swz = ((row & 7) ^ ((row >> 3) & 7)) & 7;
        *(unsigned int*)(VtB + nxt * 4096 + row * 64 + (kv2 ^ (swz << 3))) =
            (unsigned int)v0n[i] | ((unsigned int)v1n[i] << 16);
      }
    }
    // O^T[dk 64][q 32] += V^T · P^T
    __builtin_amdgcn_s_setprio(1);
#pragma unroll
    for (int ks = 0; ks < 4; ++ks)
#pragma unroll
      for (int od = 0; od < 2; ++od) {
        int vsw = ((l & 7) ^ ((od * 4) | ((l >> 3) & 3))) & 7;
        short8v vf = *(const short8v*)(
            VtB + cur * 4096 + (od * 32 + q) * 64 + ((((ks << 1) | hl) ^ vsw) << 3));
        o_acc[od] = __builtin_amdgcn_mfma_f32_32x32x16_bf16(vf, pfb[ks], o_acc[od], 0, 0, 0);
      }
    __builtin_amdgcn_s_setprio(0);
  }
  // ---- epilogue: normalize, stage O bf16 in LDS (swizzled), coalesced stores ----
  __syncthreads();
  float invl = 1.f / l_run;
  ushort* otile = lds + w * 2048;     // per-wave [32 q][64 dk]
#pragma unroll
  for (int od = 0; od < 2; ++od)
#pragma unroll
    for (int r = 0; r < 16; r += 2) {
      unsigned int pk = cvtpk(o_acc[od][r] * invl, o_acc[od][r + 1] * invl);
      int c = od * 32 + 8 * (r >> 2) + 4 * hl + (r & 3);
      *(unsigned int*)(&otile[q * 64 + (c ^ ((q & 7) << 3))]) = pk;
    }
  __syncthreads();
  {
    int r2 = l >> 1, hf = l & 1;
    ushort* orow = ao + (size_t)(b * SS + q0 + w * 32 + r2) * DD + hd * 64 + hf * 32;
#pragma unroll
    for (int k = 0; k < 4; ++k) {
      int c = hf * 32 + k * 8;
      ushort8v vv = *(const ushort8v*)(&otile[r2 * 64 + (c ^ ((r2 & 7) << 3))]);
      *(ushort8v*)(orow + k * 8) = vv;
    }
  }
}

// ---------------- residual add + layernorm (pure bf16 stream, 1 wave/row) ----------------
__global__ __launch_bounds__(64) void k_addln(ushort* __restrict__ xb,
                                              const ushort* __restrict__ y,
                                              const float* __restrict__ sc,
                                              const float* __restrict__ bi) {
  int row = blockIdx.x, l = threadIdx.x;
  int d0 = l * 12;
  ushort* xr = xb + (size_t)row * DD;
  const ushort* yr = y + (size_t)row * DD;
  ushort4v xa[3], ya[3];
#pragma unroll
  for (int j = 0; j < 3; ++j) {
    xa[j] = *(const ushort4v*)(xr + d0 + j * 4);
    ya[j] = *(const ushort4v*)(yr + d0 + j * 4);
  }
  float v[12];
  float s = 0.f;
#pragma unroll
  for (int j = 0; j < 3; ++j)
#pragma unroll
    for (int i = 0; i < 4; ++i) {
      float vv = bf2f(xa[j][i]) + bf2f(ya[j][i]);
      v[j * 4 + i] = vv;
      s += vv;
    }
  float mu = wave_sum(s);
  mu = __shfl(mu, 0) * (1.f / 768.f);
  float vs = 0.f;
#pragma unroll
  for (int i = 0; i < 12; ++i) {
    float c = v[i] - mu;
    vs += c * c;
  }
  vs = wave_sum(vs);
  float rstd = rsqrtf(__shfl(vs, 0) * (1.f / 768.f) + 1e-5f);
  float4 scv[3], biv[3];
#pragma unroll
  for (int j = 0; j < 3; ++j) {
    scv[j] = *(const float4*)(sc + d0 + j * 4);
    biv[j] = *(const float4*)(bi + d0 + j * 4);
  }
#pragma unroll
  for (int j = 0; j < 3; ++j) {
    ushort4v o;
    const float* sj = (const float*)&scv[j];
    const float* bj = (const float*)&biv[j];
#pragma unroll
    for (int i = 0; i < 4; ++i) o[i] = f2bf((v[j * 4 + i] - mu) * rstd * sj[i] + bj[i]);
    *(ushort4v*)(xr + d0 + j * 4) = o;
  }
}

// ---------------- mean pool + classifier ----------------
__global__ __launch_bounds__(256) void k_pool(const ushort* __restrict__ xb,
                                              float* __restrict__ pooled) {
  int b = blockIdx.x, chunk = blockIdx.y, t = threadIdx.x;
  float a0 = 0, a1 = 0, a2 = 0;
  for (int s2 = chunk * 128; s2 < chunk * 128 + 128; ++s2) {
    const ushort* xr = xb + (size_t)(b * SS + s2) * DD;
    a0 += bf2f(xr[t]); a1 += bf2f(xr[t + 256]); a2 += bf2f(xr[t + 512]);
  }
  atomicAdd(&pooled[b * DD + t], a0 * (1.f / 1024.f));
  atomicAdd(&pooled[b * DD + t + 256], a1 * (1.f / 1024.f));
  atomicAdd(&pooled[b * DD + t + 512], a2 * (1.f / 1024.f));
}

__global__ __launch_bounds__(64) void k_cls(const float* __restrict__ pooled,
                                            const float* __restrict__ Wc,
                                            const float* __restrict__ bc,
                                            float* __restrict__ out) {
  int idx = blockIdx.x;
  int b = idx / CC, c = idx % CC;
  int t = threadIdx.x;
  float acc = 0.f;
  for (int d0 = t; d0 < DD; d0 += 64) acc = fmaf(pooled[b * DD + d0], Wc[d0 * CC + c], acc);
  acc = wave_sum(acc);
  if (t == 0) out[b * CC + c] = acc + bc[c];
}

extern "C" void kernel_launch(void* const* d_in, const int* in_sizes, int n_in,
                              void* d_out, int out_size, void* d_ws, size_t ws_size,
                              hipStream_t stream) {
  (void)in_sizes; (void)n_in; (void)out_size; (void)ws_size;
  const int* tokens = (const int*)d_in[0];
  const float* emb = (const float*)d_in[1];
  const float* Wq = (const float*)d_in[2];
  const float* Wk = (const float*)d_in[3];
  const float* Wv = (const float*)d_in[4];
  const float* Wo = (const float*)d_in[5];
  const float* W1 = (const float*)d_in[6];
  const float* W2 = (const float*)d_in[7];
  const float* l1s = (const float*)d_in[8];
  const float* l1b = (const float*)d_in[9];
  const float* l2s = (const float*)d_in[10];
  const float* l2b = (const float*)d_in[11];
  const float* Wc = (const float*)d_in[12];
  const float* bc = (const float*)d_in[13];
  float* out = (float*)d_out;

  char* p = (char*)d_ws;
  ushort* xb = (ushort*)p;              p += (size_t)BS_ * DD * 2;
  ushort* qkvb = (ushort*)p;            // [8192][2304]
  ushort* hb = (ushort*)p;              // [8192][3072] overlay
  ushort* ao = (ushort*)(p + (size_t)BS_ * 2304 * 2);
  p += (size_t)BS_ * FF * 2;
  ushort* yb = (ushort*)p;              p += (size_t)BS_ * DD * 2;
  ushort* wt = (ushort*)p;              p += (size_t)(2304 * 768 + 768 * 768 + 3072 * 768 + 768 * 3072) * 2;
  float* pooled = (float*)p;

  ushort* wqkv_t = wt;                        // [2304][768]
  ushort* wo_t = wqkv_t + 2304 * 768;         // [768][768]
  ushort* w1_t = wo_t + 768 * 768;            // [3072][768]
  ushort* w2_t = w1_t + 3072 * 768;           // [768][3072]

  k_embed<<<BS_, 256, 0, stream>>>(tokens, emb, xb);

  for (int l = 0; l < LL; ++l) {
    k_transpose_all<<<6912, 256, 0, stream>>>(
        Wq + (size_t)l * DD * DD, Wk + (size_t)l * DD * DD,
        Wv + (size_t)l * DD * DD, Wo + (size_t)l * DD * DD,
        W1 + (size_t)l * DD * FF, W2 + (size_t)l * FF * DD,
        wqkv_t, wo_t, w1_t, w2_t);

    k_gemm_db<0, 128, 1><<<dim3(2304 / 128, BS_ / 128), 256, 0, stream>>>(xb, wqkv_t, qkvb, BS_, 2304, DD);
    k_flash<<<dim3(SS / 256, BB * HH), 512, 0, stream>>>(qkvb, ao);
    k_gemm_db<0, 64><<<dim3(DD / 64, BS_ / 128), 256, 0, stream>>>(ao, wo_t, yb, BS_, DD, DD);
    k_addln<<<BS_, 64, 0, stream>>>(xb, yb, l1s + l * DD, l1b + l * DD);
    k_gemm_db<1, 128><<<dim3(FF / 128, BS_ / 128), 256, 0, stream>>>(xb, w1_t, hb, BS_, FF, DD);
    k_gemm_db<0, 64><<<dim3(DD / 64, BS_ / 128), 256, 0, stream>>>(hb, w2_t, yb, BS_, DD, FF);
    k_addln<<<BS_, 64, 0, stream>>>(xb, yb, l2s + l * DD, l2b + l * DD);
  }

  hipMemsetAsync(pooled, 0, (size_t)BB * DD * sizeof(float), stream);
  k_pool<<<dim3(BB, 8), 256, 0, stream>>>(xb, pooled);
  k_cls<<<BB * CC, 64, 0, stream>>>(pooled, Wc, bc, out);
}

// Round 11
// 1429.692 us; speedup vs baseline: 1.0520x; 1.0520x over previous
//
#include <hip/hip_runtime.h>
#include <hip/hip_bf16.h>
#include <math.h>

#define BB 8
#define SS 1024
#define DD 768
#define HH 12
#define LL 6
#define FF 3072
#define CC 10
#define BS_ (BB * SS)   // 8192 rows

typedef __attribute__((ext_vector_type(8))) short short8v;       // bf16x8 MFMA frag
typedef __attribute__((ext_vector_type(4))) float f32x4;         // 16x16 MFMA acc
typedef __attribute__((ext_vector_type(8))) unsigned short ushort8v;
typedef __attribute__((ext_vector_type(4))) unsigned short ushort4v;
typedef __attribute__((ext_vector_type(2))) unsigned int uint2v;

#define CEXPQ 0.18033688f   // 0.125 * log2(e), folded into Q at the QKV epilogue

__device__ inline unsigned short f2bf(float f) {
  unsigned int u = __builtin_bit_cast(unsigned int, f);
  u += 0x7fffu + ((u >> 16) & 1u);
  return (unsigned short)(u >> 16);
}
__device__ inline float bf2f(unsigned short u) {
  return __builtin_bit_cast(float, (unsigned int)u << 16);
}
// pack two f32 -> two bf16 (RNE) in one u32 via v_perm
__device__ inline unsigned int pack_bf2(float lo, float hi) {
  unsigned int a = __builtin_bit_cast(unsigned int, lo);
  unsigned int b = __builtin_bit_cast(unsigned int, hi);
  a += 0x7fffu + ((a >> 16) & 1u);
  b += 0x7fffu + ((b >> 16) & 1u);
  return __builtin_amdgcn_perm(b, a, 0x07060302u);
}
__device__ inline void gload16(const void* g, void* l) {
  __builtin_amdgcn_global_load_lds((const __attribute__((address_space(1))) void*)g,
                                   (__attribute__((address_space(3))) void*)l, 16, 0, 0);
}

// ---------------- reduction helpers ----------------
__device__ inline float wave_sum(float v) {
#pragma unroll
  for (int off = 32; off > 0; off >>= 1) v += __shfl_down(v, off);
  return v;
}

// ---------------- embedding + sinusoidal PE (bf16 stream) ----------------
__global__ __launch_bounds__(256) void k_embed(const int* __restrict__ tokens,
                                               const float* __restrict__ emb,
                                               ushort* __restrict__ xb) {
  int row = blockIdx.x;
  int s = row & (SS - 1);
  int tok = tokens[row];
  const float* e = emb + (size_t)tok * DD;
  ushort* xbr = xb + (size_t)row * DD;
  for (int d = threadIdx.x; d < DD; d += 256) {
    float freq = expf((float)(d & ~1) * -0.0119926306f);
    float ang = (float)s * freq;
    float pe = (d & 1) ? cosf(ang) : sinf(ang);
    xbr[d] = f2bf(e[d] + pe);
  }
}

// ---------------- fused per-layer weight transpose ----------------
__global__ __launch_bounds__(256) void k_transpose_all(
    const float* __restrict__ wq, const float* __restrict__ wk,
    const float* __restrict__ wv, const float* __restrict__ wo,
    const float* __restrict__ w1, const float* __restrict__ w2,
    ushort* __restrict__ wqkv_t, ushort* __restrict__ wo_t,
    ushort* __restrict__ w1_t, ushort* __restrict__ w2_t) {
  __shared__ float tile[32][33];
  int bid = blockIdx.x;
  const float* W; ushort* Wt; int K, N, lb;
  if (bid < 1728) {
    int m = bid / 576; lb = bid - m * 576;
    W = (m == 0) ? wq : (m == 1) ? wk : wv;
    Wt = wqkv_t + m * 768 * 768; K = 768; N = 768;
  } else if (bid < 2304) {
    W = wo; Wt = wo_t; K = 768; N = 768; lb = bid - 1728;
  } else if (bid < 4608) {
    W = w1; Wt = w1_t; K = 768; N = 3072; lb = bid - 2304;
  } else {
    W = w2; Wt = w2_t; K = 3072; N = 768; lb = bid - 4608;
  }
  int nbk = K >> 5;
  int k0 = (lb % nbk) * 32, n0 = (lb / nbk) * 32;
  int t = threadIdx.x;
  int r = t >> 3, c4 = (t & 7) * 4;
  float4 v = *(const float4*)(W + (size_t)(k0 + r) * N + n0 + c4);
  tile[r][c4 + 0] = v.x; tile[r][c4 + 1] = v.y;
  tile[r][c4 + 2] = v.z; tile[r][c4 + 3] = v.w;
  __syncthreads();
  ushort4v o;
#pragma unroll
  for (int i = 0; i < 4; ++i) o[i] = f2bf(tile[c4 + i][r]);
  *(ushort4v*)(Wt + (size_t)(n0 + r) * K + k0 + c4) = o;
}

// ---------------- bf16 MFMA GEMM, double-buffered + T2 XOR-swizzled LDS ----------------
// SCALEQ: multiply output cols < 768 by CEXPQ (folds softmax scale into Q).
template <int RELU, int TN, int SCALEQ = 0>
__global__ __launch_bounds__(256) void k_gemm_db(const ushort* __restrict__ A,
                                                 const ushort* __restrict__ Bt,
                                                 ushort* __restrict__ Cout,
                                                 int M, int N, int K) {
  constexpr int NF = TN / 32;            // B frags per wave
  __shared__ ushort smem[2][(128 + TN) * 64];
  int bidl = blockIdx.y * gridDim.x + blockIdx.x;
  int nwg = gridDim.x * gridDim.y;
  int cpx = nwg >> 3;
  int tid = (bidl & 7) * cpx + (bidl >> 3);
  int n0 = (tid % gridDim.x) * TN, m0 = (tid / gridDim.x) * 128;
  int t = threadIdx.x, w = t >> 6, l = t & 63;
  int wr = (w >> 1) * 64, wc = (w & 1) * (TN / 2);
  int lr = l & 15, lg = l >> 4;
  f32x4 acc[4][NF] = {};
  int sr8 = l >> 3;
  int scw = ((l & 7) ^ sr8) * 8;          // inverse-swizzled source col
  const ushort* ag = A + (size_t)(m0 + w * 8 + sr8) * K + scw;
  const ushort* bg = Bt + (size_t)(n0 + w * 8 + sr8) * K + scw;
  int nk = K >> 6;
  {
    ushort* al = &smem[0][(w * 8) * 64];
    ushort* bl = &smem[0][128 * 64 + (w * 8) * 64];
#pragma unroll
    for (int ii = 0; ii < 4; ++ii) gload16(ag + (size_t)ii * 32 * K, al + ii * 2048);
#pragma unroll
    for (int ii = 0; ii < TN / 32; ++ii) gload16(bg + (size_t)ii * 32 * K, bl + ii * 2048);
  }
  int rsw = lr & 7;
  for (int k = 0; k < nk; ++k) {
    __syncthreads();
    if (k + 1 < nk) {
      int kb = (k + 1) & 1;
      int kc0 = (k + 1) * 64;
      ushort* al = &smem[kb][(w * 8) * 64];
      ushort* bl = &smem[kb][128 * 64 + (w * 8) * 64];
#pragma unroll
      for (int ii = 0; ii < 4; ++ii) gload16(ag + (size_t)ii * 32 * K + kc0, al + ii * 2048);
#pragma unroll
      for (int ii = 0; ii < TN / 32; ++ii) gload16(bg + (size_t)ii * 32 * K + kc0, bl + ii * 2048);
    }
    const ushort* As = &smem[k & 1][0];
    const ushort* Bs = &smem[k & 1][128 * 64];
#pragma unroll
    for (int ks = 0; ks < 2; ++ks) {
      short8v af[4], bfr[NF];
#pragma unroll
      for (int mi = 0; mi < 4; ++mi)
        af[mi] = *(const short8v*)(As + (wr + mi * 16 + lr) * 64 + (((ks * 4 + lg) ^ rsw) << 3));
#pragma unroll
      for (int ni = 0; ni < NF; ++ni)
        bfr[ni] = *(const short8v*)(Bs + (wc + ni * 16 + lr) * 64 + (((ks * 4 + lg) ^ rsw) << 3));
      __builtin_amdgcn_s_setprio(1);
#pragma unroll
      for (int mi = 0; mi < 4; ++mi)
#pragma unroll
        for (int ni = 0; ni < NF; ++ni)
          acc[mi][ni] = __builtin_amdgcn_mfma_f32_16x16x32_bf16(af[mi], bfr[ni], acc[mi][ni], 0, 0, 0);
      __builtin_amdgcn_s_setprio(0);
    }
  }
  __syncthreads();
  float osc = (SCALEQ && n0 < 768) ? CEXPQ : 1.0f;
  ushort* cst = &smem[0][0];
#pragma unroll
  for (int mi = 0; mi < 4; ++mi)
#pragma unroll
    for (int ni = 0; ni < NF; ++ni) {
      int cl = wc + ni * 16 + lr;
#pragma unroll
      for (int i = 0; i < 4; ++i) {
        int rl = wr + mi * 16 + lg * 4 + i;
        float v = acc[mi][ni][i];
        if (RELU) v = fmaxf(v, 0.f);
        if (SCALEQ) v *= osc;
        cst[rl * TN + (cl ^ (((rl >> 2) & 3) << 4))] = f2bf(v);
      }
    }
  __syncthreads();
  {
    int row = t >> 1, half = t & 1;
    int swr = ((row >> 2) & 3) << 4;
    ushort* crow = Cout + (size_t)(m0 + row) * N + n0 + half * (TN / 2);
#pragma unroll
    for (int c8 = 0; c8 < TN / 16; ++c8) {
      int c = half * (TN / 2) + c8 * 8;
      ushort8v vv = *(const ushort8v*)(&cst[row * TN + (c ^ swr)]);
      *(ushort8v*)(crow + c8 * 8) = vv;
    }
  }
}

// ---------------- flash attention: 16x16 MFMA, Q-tile 128, KV-tile 64 ----------------
// Round-6 structure (measured 71.3 us): 4 waves x 32 q-rows, single-buffered
// K (gload_lds, pre-swizzled source) + reg-transposed V, Ps through LDS.
// Q pre-scaled by CEXPQ in the QKV epilogue -> softmax is exp2f(s) direct.
__global__ __launch_bounds__(256) void k_flash(const ushort* __restrict__ qkv,
                                               ushort* __restrict__ ao) {
  __shared__ ushort Ks[64][64];
  __shared__ ushort Vt[64][64];
  __shared__ ushort Ps[4][32][64];
  const int LD = 2304;
  int bidl = blockIdx.y * gridDim.x + blockIdx.x;   // grid 8 x 96 = 768
  int tid = (bidl & 7) * 96 + (bidl >> 3);
  int qt = tid & 7;
  int bh = tid >> 3;
  int h = bh % HH, b = bh / HH;
  int t = threadIdx.x, w = t >> 6, l = t & 63;
  int lr = l & 15, lg = l >> 4;
  int sw = (l & 7) << 3;
  int q0 = qt * 128;
  const ushort* qbase = qkv + (size_t)(b * SS) * LD + h * 64;
  const ushort* kbase = qbase + 768;
  const ushort* vbase = qbase + 1536;
  short8v qf[2][2];
#pragma unroll
  for (int qg = 0; qg < 2; ++qg) {
    const ushort* qrow = qbase + (size_t)(q0 + w * 32 + qg * 16 + lr) * LD + lg * 8;
    qf[qg][0] = *(const short8v*)(qrow);
    qf[qg][1] = *(const short8v*)(qrow + 32);
  }
  float l_run[2] = {0.f, 0.f};
  f32x4 o_acc[2][4] = {};
  int krow_ = w * 16 + (l >> 3);
  int kcol_ = ((l & 7) * 8) ^ ((krow_ & 7) << 3);
  const ushort* kg = kbase + (size_t)krow_ * LD + kcol_;
  ushort* kl = &Ks[w * 16][0];
  int d_ = t & 7;
  int dk0 = d_ * 8;
  int kv2 = (t >> 3) * 2;
  for (int kt = 0; kt < 16; ++kt) {
    int kv0 = kt * 64;
    const ushort* vr0 = vbase + (size_t)(kv0 + kv2) * LD + dk0;
    ushort8v v0 = *(const ushort8v*)(vr0);
    ushort8v v1 = *(const ushort8v*)(vr0 + LD);
    __syncthreads();
    gload16(kg + (size_t)kv0 * LD, kl);
    gload16(kg + (size_t)(kv0 + 8) * LD, kl + 512);
#pragma unroll
    for (int i = 0; i < 8; ++i) {
      unsigned int pack = (unsigned int)v0[i] | ((unsigned int)v1[i] << 16);
      *(unsigned int*)(&Vt[dk0 + i][kv2 ^ (((i ^ d_) & 7) << 3)]) = pack;
    }
    __syncthreads();
    short8v kf[4][2];
#pragma unroll
    for (int mi = 0; mi < 4; ++mi) {
      int kvr = mi * 16 + lr;
      kf[mi][0] = *(const short8v*)(&Ks[kvr][(lg * 8) ^ sw]);
      kf[mi][1] = *(const short8v*)(&Ks[kvr][(32 + lg * 8) ^ sw]);
    }
    f32x4 s[2][4] = {};
    __builtin_amdgcn_s_setprio(1);
#pragma unroll
    for (int mi = 0; mi < 4; ++mi)
#pragma unroll
      for (int qg = 0; qg < 2; ++qg) {
        s[qg][mi] = __builtin_amdgcn_mfma_f32_16x16x32_bf16(kf[mi][0], qf[qg][0], s[qg][mi], 0, 0, 0);
        s[qg][mi] = __builtin_amdgcn_mfma_f32_16x16x32_bf16(kf[mi][1], qf[qg][1], s[qg][mi], 0, 0, 0);
      }
    __builtin_amdgcn_s_setprio(0);
#pragma unroll
    for (int qg = 0; qg < 2; ++qg) {
      float psum = 0.f;
#pragma unroll
      for (int mi = 0; mi < 4; ++mi) {
        float p0 = exp2f(s[qg][mi][0]);
        float p1 = exp2f(s[qg][mi][1]);
        float p2 = exp2f(s[qg][mi][2]);
        float p3 = exp2f(s[qg][mi][3]);
        psum += (p0 + p1) + (p2 + p3);
        uint2v pp;
        pp.x = pack_bf2(p0, p1);
        pp.y = pack_bf2(p2, p3);
        *(uint2v*)(&Ps[w][qg * 16 + lr][(mi * 16 + lg * 4) ^ ((lr & 7) << 3)]) = pp;
      }
      psum += __shfl_xor(psum, 16);
      psum += __shfl_xor(psum, 32);
      l_run[qg] += psum;
    }
#pragma unroll
    for (int ks = 0; ks < 2; ++ks) {
      short8v pf[2];
      pf[0] = *(const short8v*)(&Ps[w][lr][(ks * 32 + lg * 8) ^ sw]);
      pf[1] = *(const short8v*)(&Ps[w][16 + lr][(ks * 32 + lg * 8) ^ sw]);
      short8v vf[4];
#pragma unroll
      for (int mi = 0; mi < 4; ++mi) {
        int swz = ((lr & 7) ^ (mi * 2 + (lr >> 3))) & 7;
        vf[mi] = *(const short8v*)(&Vt[mi * 16 + lr][(ks * 32 + lg * 8) ^ (swz << 3)]);
      }
      __builtin_amdgcn_s_setprio(1);
#pragma unroll
      for (int mi = 0; mi < 4; ++mi)
#pragma unroll
        for (int qg = 0; qg < 2; ++qg)
          o_acc[qg][mi] = __builtin_amdgcn_mfma_f32_16x16x32_bf16(vf[mi], pf[qg], o_acc[qg][mi], 0, 0, 0);
      __builtin_amdgcn_s_setprio(0);
    }
  }
#pragma unroll
  for (int qg = 0; qg < 2; ++qg) {
    float invl = 1.f / l_run[qg];
    ushort* orow = ao + (size_t)(b * SS + q0 + w * 32 + qg * 16 + lr) * DD + h * 64;
#pragma unroll
    for (int mi = 0; mi < 4; ++mi) {
      ushort4v o;
#pragma unroll
      for (int i = 0; i < 4; ++i) o[i] = f2bf(o_acc[qg][mi][i] * invl);
      *(ushort4v*)(orow + mi * 16 + lg * 4) = o;
    }
  }
}

// ---------------- residual add + layernorm (pure bf16 stream, 1 wave/row) ----------------
__global__ __launch_bounds__(64) void k_addln(ushort* __restrict__ xb,
                                              const ushort* __restrict__ y,
                                              const float* __restrict__ sc,
                                              const float* __restrict__ bi) {
  int row = blockIdx.x, l = threadIdx.x;
  int d0 = l * 12;
  ushort* xr = xb + (size_t)row * DD;
  const ushort* yr = y + (size_t)row * DD;
  ushort4v xa[3], ya[3];
#pragma unroll
  for (int j = 0; j < 3; ++j) {
    xa[j] = *(const ushort4v*)(xr + d0 + j * 4);
    ya[j] = *(const ushort4v*)(yr + d0 + j * 4);
  }
  float v[12];
  float s = 0.f;
#pragma unroll
  for (int j = 0; j < 3; ++j)
#pragma unroll
    for (int i = 0; i < 4; ++i) {
      float vv = bf2f(xa[j][i]) + bf2f(ya[j][i]);
      v[j * 4 + i] = vv;
      s += vv;
    }
  float mu = wave_sum(s);
  mu = __shfl(mu, 0) * (1.f / 768.f);
  float vs = 0.f;
#pragma unroll
  for (int i = 0; i < 12; ++i) {
    float c = v[i] - mu;
    vs += c * c;
  }
  vs = wave_sum(vs);
  float rstd = rsqrtf(__shfl(vs, 0) * (1.f / 768.f) + 1e-5f);
  float4 scv[3], biv[3];
#pragma unroll
  for (int j = 0; j < 3; ++j) {
    scv[j] = *(const float4*)(sc + d0 + j * 4);
    biv[j] = *(const float4*)(bi + d0 + j * 4);
  }
#pragma unroll
  for (int j = 0; j < 3; ++j) {
    ushort4v o;
    const float* sj = (const float*)&scv[j];
    const float* bj = (const float*)&biv[j];
#pragma unroll
    for (int i = 0; i < 4; ++i) o[i] = f2bf((v[j * 4 + i] - mu) * rstd * sj[i] + bj[i]);
    *(ushort4v*)(xr + d0 + j * 4) = o;
  }
}

// ---------------- mean pool + classifier ----------------
__global__ __launch_bounds__(256) void k_pool(const ushort* __restrict__ xb,
                                              float* __restrict__ pooled) {
  int b = blockIdx.x, chunk = blockIdx.y, t = threadIdx.x;
  float a0 = 0, a1 = 0, a2 = 0;
  for (int s2 = chunk * 128; s2 < chunk * 128 + 128; ++s2) {
    const ushort* xr = xb + (size_t)(b * SS + s2) * DD;
    a0 += bf2f(xr[t]); a1 += bf2f(xr[t + 256]); a2 += bf2f(xr[t + 512]);
  }
  atomicAdd(&pooled[b * DD + t], a0 * (1.f / 1024.f));
  atomicAdd(&pooled[b * DD + t + 256], a1 * (1.f / 1024.f));
  atomicAdd(&pooled[b * DD + t + 512], a2 * (1.f / 1024.f));
}

__global__ __launch_bounds__(64) void k_cls(const float* __restrict__ pooled,
                                            const float* __restrict__ Wc,
                                            const float* __restrict__ bc,
                                            float* __restrict__ out) {
  int idx = blockIdx.x;
  int b = idx / CC, c = idx % CC;
  int t = threadIdx.x;
  float acc = 0.f;
  for (int d0 = t; d0 < DD; d0 += 64) acc = fmaf(pooled[b * DD + d0], Wc[d0 * CC + c], acc);
  acc = wave_sum(acc);
  if (t == 0) out[b * CC + c] = acc + bc[c];
}

extern "C" void kernel_launch(void* const* d_in, const int* in_sizes, int n_in,
                              void* d_out, int out_size, void* d_ws, size_t ws_size,
                              hipStream_t stream) {
  (void)in_sizes; (void)n_in; (void)out_size; (void)ws_size;
  const int* tokens = (const int*)d_in[0];
  const float* emb = (const float*)d_in[1];
  const float* Wq = (const float*)d_in[2];
  const float* Wk = (const float*)d_in[3];
  const float* Wv = (const float*)d_in[4];
  const float* Wo = (const float*)d_in[5];
  const float* W1 = (const float*)d_in[6];
  const float* W2 = (const float*)d_in[7];
  const float* l1s = (const float*)d_in[8];
  const float* l1b = (const float*)d_in[9];
  const float* l2s = (const float*)d_in[10];
  const float* l2b = (const float*)d_in[11];
  const float* Wc = (const float*)d_in[12];
  const float* bc = (const float*)d_in[13];
  float* out = (float*)d_out;

  char* p = (char*)d_ws;
  ushort* xb = (ushort*)p;              p += (size_t)BS_ * DD * 2;
  ushort* qkvb = (ushort*)p;            // [8192][2304]
  ushort* hb = (ushort*)p;              // [8192][3072] overlay
  ushort* ao = (ushort*)(p + (size_t)BS_ * 2304 * 2);
  p += (size_t)BS_ * FF * 2;
  ushort* yb = (ushort*)p;              p += (size_t)BS_ * DD * 2;
  ushort* wt = (ushort*)p;              p += (size_t)(2304 * 768 + 768 * 768 + 3072 * 768 + 768 * 3072) * 2;
  float* pooled = (float*)p;

  ushort* wqkv_t = wt;                        // [2304][768]
  ushort* wo_t = wqkv_t + 2304 * 768;         // [768][768]
  ushort* w1_t = wo_t + 768 * 768;            // [3072][768]
  ushort* w2_t = w1_t + 3072 * 768;           // [768][3072]

  k_embed<<<BS_, 256, 0, stream>>>(tokens, emb, xb);

  for (int l = 0; l < LL; ++l) {
    k_transpose_all<<<6912, 256, 0, stream>>>(
        Wq + (size_t)l * DD * DD, Wk + (size_t)l * DD * DD,
        Wv + (size_t)l * DD * DD, Wo + (size_t)l * DD * DD,
        W1 + (size_t)l * DD * FF, W2 + (size_t)l * FF * DD,
        wqkv_t, wo_t, w1_t, w2_t);

    k_gemm_db<0, 128, 1><<<dim3(2304 / 128, BS_ / 128), 256, 0, stream>>>(xb, wqkv_t, qkvb, BS_, 2304, DD);
    k_flash<<<dim3(8, BB * HH), 256, 0, stream>>>(qkvb, ao);
    k_gemm_db<0, 64><<<dim3(DD / 64, BS_ / 128), 256, 0, stream>>>(ao, wo_t, yb, BS_, DD, DD);
    k_addln<<<BS_, 64, 0, stream>>>(xb, yb, l1s + l * DD, l1b + l * DD);
    k_gemm_db<1, 128><<<dim3(FF / 128, BS_ / 128), 256, 0, stream>>>(xb, w1_t, hb, BS_, FF, DD);
    k_gemm_db<0, 64><<<dim3(DD / 64, BS_ / 128), 256, 0, stream>>>(hb, w2_t, yb, BS_, DD, FF);
    k_addln<<<BS_, 64, 0, stream>>>(xb, yb, l2s + l * DD, l2b + l * DD);
  }

  hipMemsetAsync(pooled, 0, (size_t)BB * DD * sizeof(float), stream);
  k_pool<<<dim3(BB, 8), 256, 0, stream>>>(xb, pooled);
  k_cls<<<BB * CC, 64, 0, stream>>>(pooled, Wc, bc, out);
}

// Round 12
// 1402.589 us; speedup vs baseline: 1.0723x; 1.0193x over previous
//
#include <hip/hip_runtime.h>
#include <hip/hip_bf16.h>
#include <math.h>

#define BB 8
#define SS 1024
#define DD 768
#define HH 12
#define LL 6
#define FF 3072
#define CC 10
#define BS_ (BB * SS)   // 8192 rows

// per-layer transposed-weight block (elements)
#define WT_STRIDE (2304 * 768 + 768 * 768 + 3072 * 768 + 768 * 3072)

typedef __attribute__((ext_vector_type(8))) short short8v;       // bf16x8 MFMA frag
typedef __attribute__((ext_vector_type(4))) float f32x4;         // 16x16 MFMA acc
typedef __attribute__((ext_vector_type(8))) unsigned short ushort8v;
typedef __attribute__((ext_vector_type(4))) unsigned short ushort4v;
typedef __attribute__((ext_vector_type(2))) unsigned int uint2v;

#define CEXPQ 0.18033688f   // 0.125 * log2(e), folded into Q at the QKV epilogue

__device__ inline unsigned short f2bf(float f) {
  unsigned int u = __builtin_bit_cast(unsigned int, f);
  u += 0x7fffu + ((u >> 16) & 1u);
  return (unsigned short)(u >> 16);
}
__device__ inline float bf2f(unsigned short u) {
  return __builtin_bit_cast(float, (unsigned int)u << 16);
}
// packed f32x2 -> bf16x2 (RNE) via the HW instruction
__device__ inline unsigned int cvtpk(float lo, float hi) {
  unsigned int r;
  asm("v_cvt_pk_bf16_f32 %0, %1, %2" : "=v"(r) : "v"(lo), "v"(hi));
  return r;
}
__device__ inline void gload16(const void* g, void* l) {
  __builtin_amdgcn_global_load_lds((const __attribute__((address_space(1))) void*)g,
                                   (__attribute__((address_space(3))) void*)l, 16, 0, 0);
}

// ---------------- reduction helpers ----------------
__device__ inline float wave_sum(float v) {
#pragma unroll
  for (int off = 32; off > 0; off >>= 1) v += __shfl_down(v, off);
  return v;
}

// ---------------- embedding + sinusoidal PE (bf16 stream) ----------------
__global__ __launch_bounds__(256) void k_embed(const int* __restrict__ tokens,
                                               const float* __restrict__ emb,
                                               ushort* __restrict__ xb) {
  int row = blockIdx.x;
  int s = row & (SS - 1);
  int tok = tokens[row];
  const float* e = emb + (size_t)tok * DD;
  ushort* xbr = xb + (size_t)row * DD;
  for (int d = threadIdx.x; d < DD; d += 256) {
    float freq = expf((float)(d & ~1) * -0.0119926306f);
    float ang = (float)s * freq;
    float pe = (d & 1) ? cosf(ang) : sinf(ang);
    xbr[d] = f2bf(e[d] + pe);
  }
}

// ---------------- ALL-layer weight transpose (one launch, 6912 x 6 blocks) ----------------
__global__ __launch_bounds__(256) void k_transpose_all(
    const float* __restrict__ Wq, const float* __restrict__ Wk,
    const float* __restrict__ Wv, const float* __restrict__ Wo,
    const float* __restrict__ W1, const float* __restrict__ W2,
    ushort* __restrict__ wt) {
  __shared__ float tile[32][33];
  int bid = blockIdx.x;
  int lyr = blockIdx.y;
  ushort* wqkv_t = wt + (size_t)lyr * WT_STRIDE;
  ushort* wo_t = wqkv_t + 2304 * 768;
  ushort* w1_t = wo_t + 768 * 768;
  ushort* w2_t = w1_t + 3072 * 768;
  const float* W; ushort* Wt; int K, N, lb;
  if (bid < 1728) {
    int m = bid / 576; lb = bid - m * 576;
    W = ((m == 0) ? Wq : (m == 1) ? Wk : Wv) + (size_t)lyr * DD * DD;
    Wt = wqkv_t + m * 768 * 768; K = 768; N = 768;
  } else if (bid < 2304) {
    W = Wo + (size_t)lyr * DD * DD; Wt = wo_t; K = 768; N = 768; lb = bid - 1728;
  } else if (bid < 4608) {
    W = W1 + (size_t)lyr * DD * FF; Wt = w1_t; K = 768; N = 3072; lb = bid - 2304;
  } else {
    W = W2 + (size_t)lyr * FF * DD; Wt = w2_t; K = 3072; N = 768; lb = bid - 4608;
  }
  int nbk = K >> 5;
  int k0 = (lb % nbk) * 32, n0 = (lb / nbk) * 32;
  int t = threadIdx.x;
  int r = t >> 3, c4 = (t & 7) * 4;
  float4 v = *(const float4*)(W + (size_t)(k0 + r) * N + n0 + c4);
  tile[r][c4 + 0] = v.x; tile[r][c4 + 1] = v.y;
  tile[r][c4 + 2] = v.z; tile[r][c4 + 3] = v.w;
  __syncthreads();
  ushort4v o;
#pragma unroll
  for (int i = 0; i < 4; ++i) o[i] = f2bf(tile[c4 + i][r]);
  *(ushort4v*)(Wt + (size_t)(n0 + r) * K + k0 + c4) = o;
}

// ---------------- bf16 MFMA GEMM, double-buffered + T2 XOR-swizzled LDS ----------------
// SCALEQ: multiply output cols < 768 by CEXPQ (folds softmax scale into Q).
template <int RELU, int TN, int SCALEQ = 0>
__global__ __launch_bounds__(256) void k_gemm_db(const ushort* __restrict__ A,
                                                 const ushort* __restrict__ Bt,
                                                 ushort* __restrict__ Cout,
                                                 int M, int N, int K) {
  constexpr int NF = TN / 32;            // B frags per wave
  __shared__ ushort smem[2][(128 + TN) * 64];
  int bidl = blockIdx.y * gridDim.x + blockIdx.x;
  int nwg = gridDim.x * gridDim.y;
  int cpx = nwg >> 3;
  int tid = (bidl & 7) * cpx + (bidl >> 3);
  int n0 = (tid % gridDim.x) * TN, m0 = (tid / gridDim.x) * 128;
  int t = threadIdx.x, w = t >> 6, l = t & 63;
  int wr = (w >> 1) * 64, wc = (w & 1) * (TN / 2);
  int lr = l & 15, lg = l >> 4;
  f32x4 acc[4][NF] = {};
  int sr8 = l >> 3;
  int scw = ((l & 7) ^ sr8) * 8;          // inverse-swizzled source col
  const ushort* ag = A + (size_t)(m0 + w * 8 + sr8) * K + scw;
  const ushort* bg = Bt + (size_t)(n0 + w * 8 + sr8) * K + scw;
  int nk = K >> 6;
  {
    ushort* al = &smem[0][(w * 8) * 64];
    ushort* bl = &smem[0][128 * 64 + (w * 8) * 64];
#pragma unroll
    for (int ii = 0; ii < 4; ++ii) gload16(ag + (size_t)ii * 32 * K, al + ii * 2048);
#pragma unroll
    for (int ii = 0; ii < TN / 32; ++ii) gload16(bg + (size_t)ii * 32 * K, bl + ii * 2048);
  }
  int rsw = lr & 7;
  for (int k = 0; k < nk; ++k) {
    __syncthreads();
    if (k + 1 < nk) {
      int kb = (k + 1) & 1;
      int kc0 = (k + 1) * 64;
      ushort* al = &smem[kb][(w * 8) * 64];
      ushort* bl = &smem[kb][128 * 64 + (w * 8) * 64];
#pragma unroll
      for (int ii = 0; ii < 4; ++ii) gload16(ag + (size_t)ii * 32 * K + kc0, al + ii * 2048);
#pragma unroll
      for (int ii = 0; ii < TN / 32; ++ii) gload16(bg + (size_t)ii * 32 * K + kc0, bl + ii * 2048);
    }
    const ushort* As = &smem[k & 1][0];
    const ushort* Bs = &smem[k & 1][128 * 64];
#pragma unroll
    for (int ks = 0; ks < 2; ++ks) {
      short8v af[4], bfr[NF];
#pragma unroll
      for (int mi = 0; mi < 4; ++mi)
        af[mi] = *(const short8v*)(As + (wr + mi * 16 + lr) * 64 + (((ks * 4 + lg) ^ rsw) << 3));
#pragma unroll
      for (int ni = 0; ni < NF; ++ni)
        bfr[ni] = *(const short8v*)(Bs + (wc + ni * 16 + lr) * 64 + (((ks * 4 + lg) ^ rsw) << 3));
      __builtin_amdgcn_s_setprio(1);
#pragma unroll
      for (int mi = 0; mi < 4; ++mi)
#pragma unroll
        for (int ni = 0; ni < NF; ++ni)
          acc[mi][ni] = __builtin_amdgcn_mfma_f32_16x16x32_bf16(af[mi], bfr[ni], acc[mi][ni], 0, 0, 0);
      __builtin_amdgcn_s_setprio(0);
    }
  }
  __syncthreads();
  float osc = (SCALEQ && n0 < 768) ? CEXPQ : 1.0f;
  ushort* cst = &smem[0][0];
#pragma unroll
  for (int mi = 0; mi < 4; ++mi)
#pragma unroll
    for (int ni = 0; ni < NF; ++ni) {
      int cl = wc + ni * 16 + lr;
#pragma unroll
      for (int i = 0; i < 4; ++i) {
        int rl = wr + mi * 16 + lg * 4 + i;
        float v = acc[mi][ni][i];
        if (RELU) v = fmaxf(v, 0.f);
        if (SCALEQ) v *= osc;
        cst[rl * TN + (cl ^ (((rl >> 2) & 3) << 4))] = f2bf(v);
      }
    }
  __syncthreads();
  {
    int row = t >> 1, half = t & 1;
    int swr = ((row >> 2) & 3) << 4;
    ushort* crow = Cout + (size_t)(m0 + row) * N + n0 + half * (TN / 2);
#pragma unroll
    for (int c8 = 0; c8 < TN / 16; ++c8) {
      int c = half * (TN / 2) + c8 * 8;
      ushort8v vv = *(const ushort8v*)(&cst[row * TN + (c ^ swr)]);
      *(ushort8v*)(crow + c8 * 8) = vv;
    }
  }
}

// ---------------- flash attention: 16x16 MFMA, Q-tile 128, KV-tile 64 ----------------
// r11 structure (measured 65 us); Ps packing now via v_cvt_pk_bf16_f32.
__global__ __launch_bounds__(256) void k_flash(const ushort* __restrict__ qkv,
                                               ushort* __restrict__ ao) {
  __shared__ ushort Ks[64][64];
  __shared__ ushort Vt[64][64];
  __shared__ ushort Ps[4][32][64];
  const int LD = 2304;
  int bidl = blockIdx.y * gridDim.x + blockIdx.x;   // grid 8 x 96 = 768
  int tid = (bidl & 7) * 96 + (bidl >> 3);
  int qt = tid & 7;
  int bh = tid >> 3;
  int h = bh % HH, b = bh / HH;
  int t = threadIdx.x, w = t >> 6, l = t & 63;
  int lr = l & 15, lg = l >> 4;
  int sw = (l & 7) << 3;
  int q0 = qt * 128;
  const ushort* qbase = qkv + (size_t)(b * SS) * LD + h * 64;
  const ushort* kbase = qbase + 768;
  const ushort* vbase = qbase + 1536;
  short8v qf[2][2];
#pragma unroll
  for (int qg = 0; qg < 2; ++qg) {
    const ushort* qrow = qbase + (size_t)(q0 + w * 32 + qg * 16 + lr) * LD + lg * 8;
    qf[qg][0] = *(const short8v*)(qrow);
    qf[qg][1] = *(const short8v*)(qrow + 32);
  }
  float l_run[2] = {0.f, 0.f};
  f32x4 o_acc[2][4] = {};
  int krow_ = w * 16 + (l >> 3);
  int kcol_ = ((l & 7) * 8) ^ ((krow_ & 7) << 3);
  const ushort* kg = kbase + (size_t)krow_ * LD + kcol_;
  ushort* kl = &Ks[w * 16][0];
  int d_ = t & 7;
  int dk0 = d_ * 8;
  int kv2 = (t >> 3) * 2;
  for (int kt = 0; kt < 16; ++kt) {
    int kv0 = kt * 64;
    const ushort* vr0 = vbase + (size_t)(kv0 + kv2) * LD + dk0;
    ushort8v v0 = *(const ushort8v*)(vr0);
    ushort8v v1 = *(const ushort8v*)(vr0 + LD);
    __syncthreads();
    gload16(kg + (size_t)kv0 * LD, kl);
    gload16(kg + (size_t)(kv0 + 8) * LD, kl + 512);
#pragma unroll
    for (int i = 0; i < 8; ++i) {
      unsigned int pack = (unsigned int)v0[i] | ((unsigned int)v1[i] << 16);
      *(unsigned int*)(&Vt[dk0 + i][kv2 ^ (((i ^ d_) & 7) << 3)]) = pack;
    }
    __syncthreads();
    short8v kf[4][2];
#pragma unroll
    for (int mi = 0; mi < 4; ++mi) {
      int kvr = mi * 16 + lr;
      kf[mi][0] = *(const short8v*)(&Ks[kvr][(lg * 8) ^ sw]);
      kf[mi][1] = *(const short8v*)(&Ks[kvr][(32 + lg * 8) ^ sw]);
    }
    f32x4 s[2][4] = {};
    __builtin_amdgcn_s_setprio(1);
#pragma unroll
    for (int mi = 0; mi < 4; ++mi)
#pragma unroll
      for (int qg = 0; qg < 2; ++qg) {
        s[qg][mi] = __builtin_amdgcn_mfma_f32_16x16x32_bf16(kf[mi][0], qf[qg][0], s[qg][mi], 0, 0, 0);
        s[qg][mi] = __builtin_amdgcn_mfma_f32_16x16x32_bf16(kf[mi][1], qf[qg][1], s[qg][mi], 0, 0, 0);
      }
    __builtin_amdgcn_s_setprio(0);
#pragma unroll
    for (int qg = 0; qg < 2; ++qg) {
      float psum = 0.f;
#pragma unroll
      for (int mi = 0; mi < 4; ++mi) {
        float p0 = exp2f(s[qg][mi][0]);
        float p1 = exp2f(s[qg][mi][1]);
        float p2 = exp2f(s[qg][mi][2]);
        float p3 = exp2f(s[qg][mi][3]);
        psum += (p0 + p1) + (p2 + p3);
        uint2v pp;
        pp.x = cvtpk(p0, p1);
        pp.y = cvtpk(p2, p3);
        *(uint2v*)(&Ps[w][qg * 16 + lr][(mi * 16 + lg * 4) ^ ((lr & 7) << 3)]) = pp;
      }
      psum += __shfl_xor(psum, 16);
      psum += __shfl_xor(psum, 32);
      l_run[qg] += psum;
    }
#pragma unroll
    for (int ks = 0; ks < 2; ++ks) {
      short8v pf[2];
      pf[0] = *(const short8v*)(&Ps[w][lr][(ks * 32 + lg * 8) ^ sw]);
      pf[1] = *(const short8v*)(&Ps[w][16 + lr][(ks * 32 + lg * 8) ^ sw]);
      short8v vf[4];
#pragma unroll
      for (int mi = 0; mi < 4; ++mi) {
        int swz = ((lr & 7) ^ (mi * 2 + (lr >> 3))) & 7;
        vf[mi] = *(const short8v*)(&Vt[mi * 16 + lr][(ks * 32 + lg * 8) ^ (swz << 3)]);
      }
      __builtin_amdgcn_s_setprio(1);
#pragma unroll
      for (int mi = 0; mi < 4; ++mi)
#pragma unroll
        for (int qg = 0; qg < 2; ++qg)
          o_acc[qg][mi] = __builtin_amdgcn_mfma_f32_16x16x32_bf16(vf[mi], pf[qg], o_acc[qg][mi], 0, 0, 0);
      __builtin_amdgcn_s_setprio(0);
    }
  }
#pragma unroll
  for (int qg = 0; qg < 2; ++qg) {
    float invl = 1.f / l_run[qg];
    ushort* orow = ao + (size_t)(b * SS + q0 + w * 32 + qg * 16 + lr) * DD + h * 64;
#pragma unroll
    for (int mi = 0; mi < 4; ++mi) {
      ushort4v o;
#pragma unroll
      for (int i = 0; i < 4; ++i) o[i] = f2bf(o_acc[qg][mi][i] * invl);
      *(ushort4v*)(orow + mi * 16 + lg * 4) = o;
    }
  }
}

// ---------------- residual add + layernorm (pure bf16 stream, 1 wave/row) ----------------
__global__ __launch_bounds__(64) void k_addln(ushort* __restrict__ xb,
                                              const ushort* __restrict__ y,
                                              const float* __restrict__ sc,
                                              const float* __restrict__ bi) {
  int row = blockIdx.x, l = threadIdx.x;
  int d0 = l * 12;
  ushort* xr = xb + (size_t)row * DD;
  const ushort* yr = y + (size_t)row * DD;
  ushort4v xa[3], ya[3];
#pragma unroll
  for (int j = 0; j < 3; ++j) {
    xa[j] = *(const ushort4v*)(xr + d0 + j * 4);
    ya[j] = *(const ushort4v*)(yr + d0 + j * 4);
  }
  float v[12];
  float s = 0.f;
#pragma unroll
  for (int j = 0; j < 3; ++j)
#pragma unroll
    for (int i = 0; i < 4; ++i) {
      float vv = bf2f(xa[j][i]) + bf2f(ya[j][i]);
      v[j * 4 + i] = vv;
      s += vv;
    }
  float mu = wave_sum(s);
  mu = __shfl(mu, 0) * (1.f / 768.f);
  float vs = 0.f;
#pragma unroll
  for (int i = 0; i < 12; ++i) {
    float c = v[i] - mu;
    vs += c * c;
  }
  vs = wave_sum(vs);
  float rstd = rsqrtf(__shfl(vs, 0) * (1.f / 768.f) + 1e-5f);
  float4 scv[3], biv[3];
#pragma unroll
  for (int j = 0; j < 3; ++j) {
    scv[j] = *(const float4*)(sc + d0 + j * 4);
    biv[j] = *(const float4*)(bi + d0 + j * 4);
  }
#pragma unroll
  for (int j = 0; j < 3; ++j) {
    ushort4v o;
    const float* sj = (const float*)&scv[j];
    const float* bj = (const float*)&biv[j];
#pragma unroll
    for (int i = 0; i < 4; ++i) o[i] = f2bf((v[j * 4 + i] - mu) * rstd * sj[i] + bj[i]);
    *(ushort4v*)(xr + d0 + j * 4) = o;
  }
}

// ---------------- mean pool + classifier ----------------
__global__ __launch_bounds__(256) void k_pool(const ushort* __restrict__ xb,
                                              float* __restrict__ pooled) {
  int b = blockIdx.x, chunk = blockIdx.y, t = threadIdx.x;
  float a0 = 0, a1 = 0, a2 = 0;
  for (int s2 = chunk * 128; s2 < chunk * 128 + 128; ++s2) {
    const ushort* xr = xb + (size_t)(b * SS + s2) * DD;
    a0 += bf2f(xr[t]); a1 += bf2f(xr[t + 256]); a2 += bf2f(xr[t + 512]);
  }
  atomicAdd(&pooled[b * DD + t], a0 * (1.f / 1024.f));
  atomicAdd(&pooled[b * DD + t + 256], a1 * (1.f / 1024.f));
  atomicAdd(&pooled[b * DD + t + 512], a2 * (1.f / 1024.f));
}

__global__ __launch_bounds__(64) void k_cls(const float* __restrict__ pooled,
                                            const float* __restrict__ Wc,
                                            const float* __restrict__ bc,
                                            float* __restrict__ out) {
  int idx = blockIdx.x;
  int b = idx / CC, c = idx % CC;
  int t = threadIdx.x;
  float acc = 0.f;
  for (int d0 = t; d0 < DD; d0 += 64) acc = fmaf(pooled[b * DD + d0], Wc[d0 * CC + c], acc);
  acc = wave_sum(acc);
  if (t == 0) out[b * CC + c] = acc + bc[c];
}

extern "C" void kernel_launch(void* const* d_in, const int* in_sizes, int n_in,
                              void* d_out, int out_size, void* d_ws, size_t ws_size,
                              hipStream_t stream) {
  (void)in_sizes; (void)n_in; (void)out_size; (void)ws_size;
  const int* tokens = (const int*)d_in[0];
  const float* emb = (const float*)d_in[1];
  const float* Wq = (const float*)d_in[2];
  const float* Wk = (const float*)d_in[3];
  const float* Wv = (const float*)d_in[4];
  const float* Wo = (const float*)d_in[5];
  const float* W1 = (const float*)d_in[6];
  const float* W2 = (const float*)d_in[7];
  const float* l1s = (const float*)d_in[8];
  const float* l1b = (const float*)d_in[9];
  const float* l2s = (const float*)d_in[10];
  const float* l2b = (const float*)d_in[11];
  const float* Wc = (const float*)d_in[12];
  const float* bc = (const float*)d_in[13];
  float* out = (float*)d_out;

  char* p = (char*)d_ws;
  ushort* xb = (ushort*)p;              p += (size_t)BS_ * DD * 2;
  ushort* qkvb = (ushort*)p;            // [8192][2304]
  ushort* hb = (ushort*)p;              // [8192][3072] overlay
  ushort* ao = (ushort*)(p + (size_t)BS_ * 2304 * 2);
  p += (size_t)BS_ * FF * 2;
  ushort* yb = (ushort*)p;              p += (size_t)BS_ * DD * 2;
  ushort* wt = (ushort*)p;              p += (size_t)WT_STRIDE * LL * 2;   // all 6 layers
  float* pooled = (float*)p;

  k_embed<<<BS_, 256, 0, stream>>>(tokens, emb, xb);
  // all 36 weight transposes in one launch (off the per-layer critical path)
  k_transpose_all<<<dim3(6912, LL), 256, 0, stream>>>(Wq, Wk, Wv, Wo, W1, W2, wt);

  for (int l = 0; l < LL; ++l) {
    ushort* wqkv_t = wt + (size_t)l * WT_STRIDE;   // [2304][768]
    ushort* wo_t = wqkv_t + 2304 * 768;            // [768][768]
    ushort* w1_t = wo_t + 768 * 768;               // [3072][768]
    ushort* w2_t = w1_t + 3072 * 768;              // [768][3072]

    k_gemm_db<0, 128, 1><<<dim3(2304 / 128, BS_ / 128), 256, 0, stream>>>(xb, wqkv_t, qkvb, BS_, 2304, DD);
    k_flash<<<dim3(8, BB * HH), 256, 0, stream>>>(qkvb, ao);
    k_gemm_db<0, 64><<<dim3(DD / 64, BS_ / 128), 256, 0, stream>>>(ao, wo_t, yb, BS_, DD, DD);
    k_addln<<<BS_, 64, 0, stream>>>(xb, yb, l1s + l * DD, l1b + l * DD);
    k_gemm_db<1, 128><<<dim3(FF / 128, BS_ / 128), 256, 0, stream>>>(xb, w1_t, hb, BS_, FF, DD);
    k_gemm_db<0, 64><<<dim3(DD / 64, BS_ / 128), 256, 0, stream>>>(hb, w2_t, yb, BS_, DD, FF);
    k_addln<<<BS_, 64, 0, stream>>>(xb, yb, l2s + l * DD, l2b + l * DD);
  }

  hipMemsetAsync(pooled, 0, (size_t)BB * DD * sizeof(float), stream);
  k_pool<<<dim3(BB, 8), 256, 0, stream>>>(xb, pooled);
  k_cls<<<BB * CC, 64, 0, stream>>>(pooled, Wc, bc, out);
}

// Round 13
// 1399.464 us; speedup vs baseline: 1.0747x; 1.0022x over previous
//
#include <hip/hip_runtime.h>
#include <hip/hip_bf16.h>
#include <math.h>

#define BB 8
#define SS 1024
#define DD 768
#define HH 12
#define LL 6
#define FF 3072
#define CC 10
#define BS_ (BB * SS)   // 8192 rows

// per-layer transposed-weight block (elements)
#define WT_STRIDE (2304 * 768 + 768 * 768 + 3072 * 768 + 768 * 3072)

typedef __attribute__((ext_vector_type(8))) short short8v;       // bf16x8 MFMA frag
typedef __attribute__((ext_vector_type(4))) float f32x4;         // 16x16 MFMA acc
typedef __attribute__((ext_vector_type(8))) unsigned short ushort8v;
typedef __attribute__((ext_vector_type(4))) unsigned short ushort4v;
typedef __attribute__((ext_vector_type(2))) unsigned int uint2v;

#define CEXPQ 0.18033688f   // 0.125 * log2(e), folded into Q at the QKV epilogue

__device__ inline unsigned short f2bf(float f) {
  unsigned int u = __builtin_bit_cast(unsigned int, f);
  u += 0x7fffu + ((u >> 16) & 1u);
  return (unsigned short)(u >> 16);
}
__device__ inline float bf2f(unsigned short u) {
  return __builtin_bit_cast(float, (unsigned int)u << 16);
}
// packed f32x2 -> bf16x2 (RNE) via the HW instruction
__device__ inline unsigned int cvtpk(float lo, float hi) {
  unsigned int r;
  asm("v_cvt_pk_bf16_f32 %0, %1, %2" : "=v"(r) : "v"(lo), "v"(hi));
  return r;
}
__device__ inline void gload16(const void* g, void* l) {
  __builtin_amdgcn_global_load_lds((const __attribute__((address_space(1))) void*)g,
                                   (__attribute__((address_space(3))) void*)l, 16, 0, 0);
}

// ---------------- reduction helpers ----------------
__device__ inline float wave_sum(float v) {
#pragma unroll
  for (int off = 32; off > 0; off >>= 1) v += __shfl_down(v, off);
  return v;
}

// ---------------- embedding + sinusoidal PE (bf16 stream) ----------------
__global__ __launch_bounds__(256) void k_embed(const int* __restrict__ tokens,
                                               const float* __restrict__ emb,
                                               ushort* __restrict__ xb) {
  int row = blockIdx.x;
  int s = row & (SS - 1);
  int tok = tokens[row];
  const float* e = emb + (size_t)tok * DD;
  ushort* xbr = xb + (size_t)row * DD;
  for (int d = threadIdx.x; d < DD; d += 256) {
    float freq = expf((float)(d & ~1) * -0.0119926306f);
    float ang = (float)s * freq;
    float pe = (d & 1) ? cosf(ang) : sinf(ang);
    xbr[d] = f2bf(e[d] + pe);
  }
}

// ---------------- ALL-layer weight transpose: 64x64 tiles, one launch ----------------
// grid = (1728, 6): per layer 432 qkv + 144 wo + 576 w1 + 576 w2 tiles.
__global__ __launch_bounds__(256) void k_transpose_all(
    const float* __restrict__ Wq, const float* __restrict__ Wk,
    const float* __restrict__ Wv, const float* __restrict__ Wo,
    const float* __restrict__ W1, const float* __restrict__ W2,
    ushort* __restrict__ wt) {
  __shared__ float tile[64][65];
  int bid = blockIdx.x;
  int lyr = blockIdx.y;
  ushort* wqkv_t = wt + (size_t)lyr * WT_STRIDE;
  ushort* wo_t = wqkv_t + 2304 * 768;
  ushort* w1_t = wo_t + 768 * 768;
  ushort* w2_t = w1_t + 3072 * 768;
  const float* W; ushort* Wt; int K, N, lb;
  if (bid < 432) {
    int m = bid / 144; lb = bid - m * 144;
    W = ((m == 0) ? Wq : (m == 1) ? Wk : Wv) + (size_t)lyr * DD * DD;
    Wt = wqkv_t + m * 768 * 768; K = 768; N = 768;
  } else if (bid < 576) {
    W = Wo + (size_t)lyr * DD * DD; Wt = wo_t; K = 768; N = 768; lb = bid - 432;
  } else if (bid < 1152) {
    W = W1 + (size_t)lyr * DD * FF; Wt = w1_t; K = 768; N = 3072; lb = bid - 576;
  } else {
    W = W2 + (size_t)lyr * FF * DD; Wt = w2_t; K = 3072; N = 768; lb = bid - 1152;
  }
  int nbk = K >> 6;
  int k0 = (lb % nbk) * 64, n0 = (lb / nbk) * 64;
  int t = threadIdx.x;
  {  // load 64x64 f32 tile, coalesced: 4 threads/row x 4 float4
    int r = t >> 2, cl = (t & 3) * 16;
    const float* wrow = W + (size_t)(k0 + r) * N + n0 + cl;
#pragma unroll
    for (int j = 0; j < 4; ++j) {
      float4 v = *(const float4*)(wrow + j * 4);
      tile[r][cl + j * 4 + 0] = v.x; tile[r][cl + j * 4 + 1] = v.y;
      tile[r][cl + j * 4 + 2] = v.z; tile[r][cl + j * 4 + 3] = v.w;
    }
  }
  __syncthreads();
  {  // write transposed bf16: 4 threads/output-row x 2 ushort8v
    int n = t >> 2, cq = (t & 3) * 16;
    ushort8v o0, o1;
#pragma unroll
    for (int jj = 0; jj < 8; ++jj) o0[jj] = f2bf(tile[cq + jj][n]);
#pragma unroll
    for (int jj = 0; jj < 8; ++jj) o1[jj] = f2bf(tile[cq + 8 + jj][n]);
    ushort* orow = Wt + (size_t)(n0 + n) * K + k0 + cq;
    *(ushort8v*)(orow) = o0;
    *(ushort8v*)(orow + 8) = o1;
  }
}

// ---------------- bf16 MFMA GEMM: dbuf + counted vmcnt (T3/T4), T2 swizzle ----------------
// Per K-step: wait vmcnt(LOADS) [tile k landed, tile k+1 in flight] -> barrier
// -> ds_read ALL frags to regs -> lgkmcnt(0) + barrier [buffer free] ->
// issue stage(k+2) into freed buffer -> pure-reg MFMA. Never drains the
// just-issued prefetch: each stage has TWO compute phases to fly.
template <int RELU, int TN, int SCALEQ = 0>
__global__ __launch_bounds__(256) void k_gemm_db(const ushort* __restrict__ A,
                                                 const ushort* __restrict__ Bt,
                                                 ushort* __restrict__ Cout,
                                                 int M, int N, int K) {
  constexpr int NF = TN / 32;            // B frags per wave
  __shared__ ushort smem[2][(128 + TN) * 64];
  int bidl = blockIdx.y * gridDim.x + blockIdx.x;
  int nwg = gridDim.x * gridDim.y;
  int cpx = nwg >> 3;
  int tid = (bidl & 7) * cpx + (bidl >> 3);
  int n0 = (tid % gridDim.x) * TN, m0 = (tid / gridDim.x) * 128;
  int t = threadIdx.x, w = t >> 6, l = t & 63;
  int wr = (w >> 1) * 64, wc = (w & 1) * (TN / 2);
  int lr = l & 15, lg = l >> 4;
  f32x4 acc[4][NF] = {};
  int sr8 = l >> 3;
  int scw = ((l & 7) ^ sr8) * 8;          // inverse-swizzled source col
  const ushort* ag = A + (size_t)(m0 + w * 8 + sr8) * K + scw;
  const ushort* bg = Bt + (size_t)(n0 + w * 8 + sr8) * K + scw;
  int nk = K >> 6;

#define STAGE_TILE(KC0, BUF)                                                     \
  {                                                                              \
    ushort* al = &smem[BUF][(w * 8) * 64];                                       \
    ushort* bl = &smem[BUF][128 * 64 + (w * 8) * 64];                            \
    _Pragma("unroll") for (int ii = 0; ii < 4; ++ii)                             \
        gload16(ag + (size_t)ii * 32 * K + (KC0), al + ii * 2048);               \
    _Pragma("unroll") for (int ii = 0; ii < TN / 32; ++ii)                       \
        gload16(bg + (size_t)ii * 32 * K + (KC0), bl + ii * 2048);               \
  }

  // prologue: stage tiles 0 and 1
  STAGE_TILE(0, 0);
  if (nk > 1) STAGE_TILE(64, 1);
  int rsw = lr & 7;
  for (int k = 0; k < nk; ++k) {
    // wait for tile k only; leave tile k+1's loads (if any) in flight
    if (k + 1 < nk) {
      if constexpr (TN == 128) asm volatile("s_waitcnt vmcnt(8)" ::: "memory");
      else                     asm volatile("s_waitcnt vmcnt(6)" ::: "memory");
    } else {
      asm volatile("s_waitcnt vmcnt(0)" ::: "memory");
    }
    __builtin_amdgcn_s_barrier();
    __builtin_amdgcn_sched_barrier(0);
    const ushort* As = &smem[k & 1][0];
    const ushort* Bs = &smem[k & 1][128 * 64];
    short8v af[2][4], bfr[2][NF];
#pragma unroll
    for (int ks = 0; ks < 2; ++ks) {
#pragma unroll
      for (int mi = 0; mi < 4; ++mi)
        af[ks][mi] = *(const short8v*)(As + (wr + mi * 16 + lr) * 64 + (((ks * 4 + lg) ^ rsw) << 3));
#pragma unroll
      for (int ni = 0; ni < NF; ++ni)
        bfr[ks][ni] = *(const short8v*)(Bs + (wc + ni * 16 + lr) * 64 + (((ks * 4 + lg) ^ rsw) << 3));
    }
    asm volatile("s_waitcnt lgkmcnt(0)" ::: "memory");
    __builtin_amdgcn_s_barrier();        // all waves' frag reads done: buffer free
    __builtin_amdgcn_sched_barrier(0);
    if (k + 2 < nk) STAGE_TILE((k + 2) * 64, k & 1);
    __builtin_amdgcn_s_setprio(1);
#pragma unroll
    for (int ks = 0; ks < 2; ++ks)
#pragma unroll
      for (int mi = 0; mi < 4; ++mi)
#pragma unroll
        for (int ni = 0; ni < NF; ++ni)
          acc[mi][ni] = __builtin_amdgcn_mfma_f32_16x16x32_bf16(af[ks][mi], bfr[ks][ni], acc[mi][ni], 0, 0, 0);
    __builtin_amdgcn_s_setprio(0);
  }
#undef STAGE_TILE
  __syncthreads();
  float osc = (SCALEQ && n0 < 768) ? CEXPQ : 1.0f;
  ushort* cst = &smem[0][0];
#pragma unroll
  for (int mi = 0; mi < 4; ++mi)
#pragma unroll
    for (int ni = 0; ni < NF; ++ni) {
      int cl = wc + ni * 16 + lr;
#pragma unroll
      for (int i = 0; i < 4; ++i) {
        int rl = wr + mi * 16 + lg * 4 + i;
        float v = acc[mi][ni][i];
        if (RELU) v = fmaxf(v, 0.f);
        if (SCALEQ) v *= osc;
        cst[rl * TN + (cl ^ (((rl >> 2) & 3) << 4))] = f2bf(v);
      }
    }
  __syncthreads();
  {
    int row = t >> 1, half = t & 1;
    int swr = ((row >> 2) & 3) << 4;
    ushort* crow = Cout + (size_t)(m0 + row) * N + n0 + half * (TN / 2);
#pragma unroll
    for (int c8 = 0; c8 < TN / 16; ++c8) {
      int c = half * (TN / 2) + c8 * 8;
      ushort8v vv = *(const ushort8v*)(&cst[row * TN + (c ^ swr)]);
      *(ushort8v*)(crow + c8 * 8) = vv;
    }
  }
}

// ---------------- flash attention: 16x16 MFMA, Q-tile 128, KV-tile 64 ----------------
// r11 structure (measured 65 us), unchanged.
__global__ __launch_bounds__(256) void k_flash(const ushort* __restrict__ qkv,
                                               ushort* __restrict__ ao) {
  __shared__ ushort Ks[64][64];
  __shared__ ushort Vt[64][64];
  __shared__ ushort Ps[4][32][64];
  const int LD = 2304;
  int bidl = blockIdx.y * gridDim.x + blockIdx.x;   // grid 8 x 96 = 768
  int tid = (bidl & 7) * 96 + (bidl >> 3);
  int qt = tid & 7;
  int bh = tid >> 3;
  int h = bh % HH, b = bh / HH;
  int t = threadIdx.x, w = t >> 6, l = t & 63;
  int lr = l & 15, lg = l >> 4;
  int sw = (l & 7) << 3;
  int q0 = qt * 128;
  const ushort* qbase = qkv + (size_t)(b * SS) * LD + h * 64;
  const ushort* kbase = qbase + 768;
  const ushort* vbase = qbase + 1536;
  short8v qf[2][2];
#pragma unroll
  for (int qg = 0; qg < 2; ++qg) {
    const ushort* qrow = qbase + (size_t)(q0 + w * 32 + qg * 16 + lr) * LD + lg * 8;
    qf[qg][0] = *(const short8v*)(qrow);
    qf[qg][1] = *(const short8v*)(qrow + 32);
  }
  float l_run[2] = {0.f, 0.f};
  f32x4 o_acc[2][4] = {};
  int krow_ = w * 16 + (l >> 3);
  int kcol_ = ((l & 7) * 8) ^ ((krow_ & 7) << 3);
  const ushort* kg = kbase + (size_t)krow_ * LD + kcol_;
  ushort* kl = &Ks[w * 16][0];
  int d_ = t & 7;
  int dk0 = d_ * 8;
  int kv2 = (t >> 3) * 2;
  for (int kt = 0; kt < 16; ++kt) {
    int kv0 = kt * 64;
    const ushort* vr0 = vbase + (size_t)(kv0 + kv2) * LD + dk0;
    ushort8v v0 = *(const ushort8v*)(vr0);
    ushort8v v1 = *(const ushort8v*)(vr0 + LD);
    __syncthreads();
    gload16(kg + (size_t)kv0 * LD, kl);
    gload16(kg + (size_t)(kv0 + 8) * LD, kl + 512);
#pragma unroll
    for (int i = 0; i < 8; ++i) {
      unsigned int pack = (unsigned int)v0[i] | ((unsigned int)v1[i] << 16);
      *(unsigned int*)(&Vt[dk0 + i][kv2 ^ (((i ^ d_) & 7) << 3)]) = pack;
    }
    __syncthreads();
    short8v kf[4][2];
#pragma unroll
    for (int mi = 0; mi < 4; ++mi) {
      int kvr = mi * 16 + lr;
      kf[mi][0] = *(const short8v*)(&Ks[kvr][(lg * 8) ^ sw]);
      kf[mi][1] = *(const short8v*)(&Ks[kvr][(32 + lg * 8) ^ sw]);
    }
    f32x4 s[2][4] = {};
    __builtin_amdgcn_s_setprio(1);
#pragma unroll
    for (int mi = 0; mi < 4; ++mi)
#pragma unroll
      for (int qg = 0; qg < 2; ++qg) {
        s[qg][mi] = __builtin_amdgcn_mfma_f32_16x16x32_bf16(kf[mi][0], qf[qg][0], s[qg][mi], 0, 0, 0);
        s[qg][mi] = __builtin_amdgcn_mfma_f32_16x16x32_bf16(kf[mi][1], qf[qg][1], s[qg][mi], 0, 0, 0);
      }
    __builtin_amdgcn_s_setprio(0);
#pragma unroll
    for (int qg = 0; qg < 2; ++qg) {
      float psum = 0.f;
#pragma unroll
      for (int mi = 0; mi < 4; ++mi) {
        float p0 = exp2f(s[qg][mi][0]);
        float p1 = exp2f(s[qg][mi][1]);
        float p2 = exp2f(s[qg][mi][2]);
        float p3 = exp2f(s[qg][mi][3]);
        psum += (p0 + p1) + (p2 + p3);
        uint2v pp;
        pp.x = cvtpk(p0, p1);
        pp.y = cvtpk(p2, p3);
        *(uint2v*)(&Ps[w][qg * 16 + lr][(mi * 16 + lg * 4) ^ ((lr & 7) << 3)]) = pp;
      }
      psum += __shfl_xor(psum, 16);
      psum += __shfl_xor(psum, 32);
      l_run[qg] += psum;
    }
#pragma unroll
    for (int ks = 0; ks < 2; ++ks) {
      short8v pf[2];
      pf[0] = *(const short8v*)(&Ps[w][lr][(ks * 32 + lg * 8) ^ sw]);
      pf[1] = *(const short8v*)(&Ps[w][16 + lr][(ks * 32 + lg * 8) ^ sw]);
      short8v vf[4];
#pragma unroll
      for (int mi = 0; mi < 4; ++mi) {
        int swz = ((lr & 7) ^ (mi * 2 + (lr >> 3))) & 7;
        vf[mi] = *(const short8v*)(&Vt[mi * 16 + lr][(ks * 32 + lg * 8) ^ (swz << 3)]);
      }
      __builtin_amdgcn_s_setprio(1);
#pragma unroll
      for (int mi = 0; mi < 4; ++mi)
#pragma unroll
        for (int qg = 0; qg < 2; ++qg)
          o_acc[qg][mi] = __builtin_amdgcn_mfma_f32_16x16x32_bf16(vf[mi], pf[qg], o_acc[qg][mi], 0, 0, 0);
      __builtin_amdgcn_s_setprio(0);
    }
  }
#pragma unroll
  for (int qg = 0; qg < 2; ++qg) {
    float invl = 1.f / l_run[qg];
    ushort* orow = ao + (size_t)(b * SS + q0 + w * 32 + qg * 16 + lr) * DD + h * 64;
#pragma unroll
    for (int mi = 0; mi < 4; ++mi) {
      ushort4v o;
#pragma unroll
      for (int i = 0; i < 4; ++i) o[i] = f2bf(o_acc[qg][mi][i] * invl);
      *(ushort4v*)(orow + mi * 16 + lg * 4) = o;
    }
  }
}

// ---------------- residual add + layernorm (pure bf16 stream, 1 wave/row) ----------------
__global__ __launch_bounds__(64) void k_addln(ushort* __restrict__ xb,
                                              const ushort* __restrict__ y,
                                              const float* __restrict__ sc,
                                              const float* __restrict__ bi) {
  int row = blockIdx.x, l = threadIdx.x;
  int d0 = l * 12;
  ushort* xr = xb + (size_t)row * DD;
  const ushort* yr = y + (size_t)row * DD;
  ushort4v xa[3], ya[3];
#pragma unroll
  for (int j = 0; j < 3; ++j) {
    xa[j] = *(const ushort4v*)(xr + d0 + j * 4);
    ya[j] = *(const ushort4v*)(yr + d0 + j * 4);
  }
  float v[12];
  float s = 0.f;
#pragma unroll
  for (int j = 0; j < 3; ++j)
#pragma unroll
    for (int i = 0; i < 4; ++i) {
      float vv = bf2f(xa[j][i]) + bf2f(ya[j][i]);
      v[j * 4 + i] = vv;
      s += vv;
    }
  float mu = wave_sum(s);
  mu = __shfl(mu, 0) * (1.f / 768.f);
  float vs = 0.f;
#pragma unroll
  for (int i = 0; i < 12; ++i) {
    float c = v[i] - mu;
    vs += c * c;
  }
  vs = wave_sum(vs);
  float rstd = rsqrtf(__shfl(vs, 0) * (1.f / 768.f) + 1e-5f);
  float4 scv[3], biv[3];
#pragma unroll
  for (int j = 0; j < 3; ++j) {
    scv[j] = *(const float4*)(sc + d0 + j * 4);
    biv[j] = *(const float4*)(bi + d0 + j * 4);
  }
#pragma unroll
  for (int j = 0; j < 3; ++j) {
    ushort4v o;
    const float* sj = (const float*)&scv[j];
    const float* bj = (const float*)&biv[j];
#pragma unroll
    for (int i = 0; i < 4; ++i) o[i] = f2bf((v[j * 4 + i] - mu) * rstd * sj[i] + bj[i]);
    *(ushort4v*)(xr + d0 + j * 4) = o;
  }
}

// ---------------- mean pool + classifier ----------------
__global__ __launch_bounds__(256) void k_pool(const ushort* __restrict__ xb,
                                              float* __restrict__ pooled) {
  int b = blockIdx.x, chunk = blockIdx.y, t = threadIdx.x;
  float a0 = 0, a1 = 0, a2 = 0;
  for (int s2 = chunk * 128; s2 < chunk * 128 + 128; ++s2) {
    const ushort* xr = xb + (size_t)(b * SS + s2) * DD;
    a0 += bf2f(xr[t]); a1 += bf2f(xr[t + 256]); a2 += bf2f(xr[t + 512]);
  }
  atomicAdd(&pooled[b * DD + t], a0 * (1.f / 1024.f));
  atomicAdd(&pooled[b * DD + t + 256], a1 * (1.f / 1024.f));
  atomicAdd(&pooled[b * DD + t + 512], a2 * (1.f / 1024.f));
}

__global__ __launch_bounds__(64) void k_cls(const float* __restrict__ pooled,
                                            const float* __restrict__ Wc,
                                            const float* __restrict__ bc,
                                            float* __restrict__ out) {
  int idx = blockIdx.x;
  int b = idx / CC, c = idx % CC;
  int t = threadIdx.x;
  float acc = 0.f;
  for (int d0 = t; d0 < DD; d0 += 64) acc = fmaf(pooled[b * DD + d0], Wc[d0 * CC + c], acc);
  acc = wave_sum(acc);
  if (t == 0) out[b * CC + c] = acc + bc[c];
}

extern "C" void kernel_launch(void* const* d_in, const int* in_sizes, int n_in,
                              void* d_out, int out_size, void* d_ws, size_t ws_size,
                              hipStream_t stream) {
  (void)in_sizes; (void)n_in; (void)out_size; (void)ws_size;
  const int* tokens = (const int*)d_in[0];
  const float* emb = (const float*)d_in[1];
  const float* Wq = (const float*)d_in[2];
  const float* Wk = (const float*)d_in[3];
  const float* Wv = (const float*)d_in[4];
  const float* Wo = (const float*)d_in[5];
  const float* W1 = (const float*)d_in[6];
  const float* W2 = (const float*)d_in[7];
  const float* l1s = (const float*)d_in[8];
  const float* l1b = (const float*)d_in[9];
  const float* l2s = (const float*)d_in[10];
  const float* l2b = (const float*)d_in[11];
  const float* Wc = (const float*)d_in[12];
  const float* bc = (const float*)d_in[13];
  float* out = (float*)d_out;

  char* p = (char*)d_ws;
  ushort* xb = (ushort*)p;              p += (size_t)BS_ * DD * 2;
  ushort* qkvb = (ushort*)p;            // [8192][2304]
  ushort* hb = (ushort*)p;              // [8192][3072] overlay
  ushort* ao = (ushort*)(p + (size_t)BS_ * 2304 * 2);
  p += (size_t)BS_ * FF * 2;
  ushort* yb = (ushort*)p;              p += (size_t)BS_ * DD * 2;
  ushort* wt = (ushort*)p;              p += (size_t)WT_STRIDE * LL * 2;   // all 6 layers
  float* pooled = (float*)p;

  k_embed<<<BS_, 256, 0, stream>>>(tokens, emb, xb);
  k_transpose_all<<<dim3(1728, LL), 256, 0, stream>>>(Wq, Wk, Wv, Wo, W1, W2, wt);

  for (int l = 0; l < LL; ++l) {
    ushort* wqkv_t = wt + (size_t)l * WT_STRIDE;   // [2304][768]
    ushort* wo_t = wqkv_t + 2304 * 768;            // [768][768]
    ushort* w1_t = wo_t + 768 * 768;               // [3072][768]
    ushort* w2_t = w1_t + 3072 * 768;              // [768][3072]

    k_gemm_db<0, 128, 1><<<dim3(2304 / 128, BS_ / 128), 256, 0, stream>>>(xb, wqkv_t, qkvb, BS_, 2304, DD);
    k_flash<<<dim3(8, BB * HH), 256, 0, stream>>>(qkvb, ao);
    k_gemm_db<0, 64><<<dim3(DD / 64, BS_ / 128), 256, 0, stream>>>(ao, wo_t, yb, BS_, DD, DD);
    k_addln<<<BS_, 64, 0, stream>>>(xb, yb, l1s + l * DD, l1b + l * DD);
    k_gemm_db<1, 128><<<dim3(FF / 128, BS_ / 128), 256, 0, stream>>>(xb, w1_t, hb, BS_, FF, DD);
    k_gemm_db<0, 64><<<dim3(DD / 64, BS_ / 128), 256, 0, stream>>>(hb, w2_t, yb, BS_, DD, FF);
    k_addln<<<BS_, 64, 0, stream>>>(xb, yb, l2s + l * DD, l2b + l * DD);
  }

  hipMemsetAsync(pooled, 0, (size_t)BB * DD * sizeof(float), stream);
  k_pool<<<dim3(BB, 8), 256, 0, stream>>>(xb, pooled);
  k_cls<<<BB * CC, 64, 0, stream>>>(pooled, Wc, bc, out);
}